// Round 3
// baseline (1920.055 us; speedup 1.0000x reference)
//
#include <hip/hip_runtime.h>

// ---------------------------------------------------------------------------
// WordEncoder round 3: fused FFN (FFN1+gelu+FFN2+res+LN), register-resident
// GEMM mainloops (no LDS staging), swapped-acc vectorized epilogues.
// ---------------------------------------------------------------------------

#define S_LEN 8192
#define BATCH 4
#define DMODEL 256
#define NHEAD 8
#define WIN 64
#define NWIN 128
#define NLAYER 6
#define FFDIM 1024
#define MROWS (BATCH * S_LEN)

typedef float __attribute__((ext_vector_type(4))) f32x4;
typedef unsigned short u16;
typedef unsigned short __attribute__((ext_vector_type(4))) u16x4;

__device__ __forceinline__ u16 f2bf(float f) {
  unsigned u = __builtin_bit_cast(unsigned, f);
  u += 0x7fffu + ((u >> 16) & 1u);
  return (u16)(u >> 16);
}

// mfma16(d, P, Q): D rows (lane>>4)*4+j <- P's index; D cols (lane&15) <- Q's.
// Convention used below: P = col-fragment, Q = row-fragment, so each lane
// holds C[row = l15 (+16m)][4 consecutive cols = l4*4+j (+16n)].
__device__ __forceinline__ void mfma16(f32x4& d, f32x4 a, f32x4 b) {
  asm volatile("v_mfma_f32_16x16x32_bf16 %0, %1, %2, %0"
               : "+v"(d) : "v"(a), "v"(b));
}
#define MFMA_FENCE() asm volatile("s_nop 7\n\ts_nop 7")

__device__ __forceinline__ void gload_lds16(const void* g, void* l) {
  __builtin_amdgcn_global_load_lds(
      (__attribute__((address_space(1))) void*)g,
      (__attribute__((address_space(3))) void*)l, 16, 0, 0);
}

__device__ __forceinline__ float gelu_f(float t) {
  float u = 0.7978845608028654f * (t + 0.044715f * t * t * t);
  float e = __expf(2.0f * u);
  float th = 1.0f - 2.0f / (e + 1.0f);
  return 0.5f * t * (1.0f + th);
}

// -------------------------------------------------- embed + LN1(layer 0) ---
__global__ __launch_bounds__(256) void embed_ln_kernel(
    const int* __restrict__ ids, const float* __restrict__ emb,
    const float* __restrict__ pos, const float* __restrict__ g,
    const float* __restrict__ b, float* __restrict__ x, u16* __restrict__ xb) {
  int wid = threadIdx.x >> 6, lane = threadIdx.x & 63;
  int r = blockIdx.x * 4 + wid;
  int s = r & (S_LEN - 1);
  int id = ids[r];
  f32x4 e = *(const f32x4*)(emb + (size_t)id * DMODEL + lane * 4);
  f32x4 p = *(const f32x4*)(pos + (size_t)s * DMODEL + lane * 4);
  f32x4 v = e + p;
  *(f32x4*)(x + (size_t)r * DMODEL + lane * 4) = v;
  float sm = v[0] + v[1] + v[2] + v[3];
  float q = v[0] * v[0] + v[1] * v[1] + v[2] * v[2] + v[3] * v[3];
  for (int off = 32; off; off >>= 1) {
    sm += __shfl_xor(sm, off, 64);
    q += __shfl_xor(q, off, 64);
  }
  float mean = sm * (1.0f / DMODEL);
  float var = q * (1.0f / DMODEL) - mean * mean;
  float rs = rsqrtf(var + 1e-5f);
  f32x4 gg = *(const f32x4*)(g + lane * 4);
  f32x4 bb = *(const f32x4*)(b + lane * 4);
  u16x4 o;
  for (int j = 0; j < 4; ++j) o[j] = f2bf((v[j] - mean) * rs * gg[j] + bb[j]);
  *(u16x4*)(xb + (size_t)r * DMODEL + lane * 4) = o;
}

// ----------------------------------------------------------------- zero ----
__global__ void zero_kernel(float* __restrict__ p, int n4) {
  int i = blockIdx.x * blockDim.x + threadIdx.x;
  int stride = gridDim.x * blockDim.x;
  f32x4 z = {0.f, 0.f, 0.f, 0.f};
  for (; i < n4; i += stride) ((f32x4*)p)[i] = z;
}

// ------------------------------------------------- weight transpose+cast ---
__global__ void tcast_kernel(const float* __restrict__ src, u16* __restrict__ dst,
                             int total, int K, int N, int dls, int rowOff) {
  int i = blockIdx.x * blockDim.x + threadIdx.x;
  int stride = gridDim.x * blockDim.x;
  int KN = K * N;
  for (; i < total; i += stride) {
    int l = i / KN;
    int rem = i - l * KN;
    int k = rem / N;
    int n = rem - k * N;
    dst[l * dls + (rowOff + n) * K + k] = f2bf(src[i]);
  }
}

// ----------------------------------------------------------- QKV GEMM ------
// out[M][768] tile: 64 rows x 256 cols per block. 4 waves split cols.
// Register mainloop (K=256), LDS-staged bf16 epilogue for full-line stores.
#define QOST 280  // OutS row stride in u16 (560 B = 140 dw == 12 banks/row)
__global__ __launch_bounds__(256) void qkv_gemm(
    const u16* __restrict__ A, const u16* __restrict__ Wt,
    u16* __restrict__ out) {
  __shared__ u16 OutS[64 * QOST];
  int nwg = gridDim.x;  // 1536, divisible by 8
  int bid = blockIdx.x;
  int w8 = (bid & 7) * (nwg >> 3) + (bid >> 3);
  int cx = w8 % 3, ry = w8 / 3;
  int bm = ry * 64, bn = cx * 256;

  int tid = threadIdx.x, lane = tid & 63, w = tid >> 6;
  int l15 = lane & 15, l4 = lane >> 4;

  const u16* Ab = A + (size_t)bm * 256;
  const u16* Wb = Wt + (size_t)(bn + w * 64) * 256;

  f32x4 acc[4][4] = {};
#pragma unroll
  for (int kk = 0; kk < 8; ++kk) {
    f32x4 af[4], bf[4];
#pragma unroll
    for (int m = 0; m < 4; ++m)
      af[m] = *(const f32x4*)(Ab + (m * 16 + l15) * 256 + kk * 32 + l4 * 8);
#pragma unroll
    for (int n = 0; n < 4; ++n)
      bf[n] = *(const f32x4*)(Wb + (n * 16 + l15) * 256 + kk * 32 + l4 * 8);
#pragma unroll
    for (int m = 0; m < 4; ++m)
#pragma unroll
      for (int n = 0; n < 4; ++n) mfma16(acc[m][n], bf[n], af[m]);
  }
  MFMA_FENCE();

#pragma unroll
  for (int m = 0; m < 4; ++m)
#pragma unroll
    for (int n = 0; n < 4; ++n) {
      u16x4 o;
#pragma unroll
      for (int j = 0; j < 4; ++j) o[j] = f2bf(acc[m][n][j]);
      *(u16x4*)(OutS + (m * 16 + l15) * QOST + w * 64 + n * 16 + l4 * 4) = o;
    }
  __syncthreads();
#pragma unroll
  for (int i = 0; i < 8; ++i) {
    int q = tid + i * 256;        // 2048 chunks of 16 B
    int r = q >> 5, cc = q & 31;  // row 0..63, col-chunk 0..31
    *(f32x4*)(out + (size_t)(bm + r) * 768 + bn + cc * 8) =
        *(const f32x4*)(OutS + r * QOST + cc * 8);
  }
}

// ---------------------------------------------- WO GEMM + residual + LN ----
// x += ao @ WoT^T ; xb = LN(x). 64 rows/block, 4 waves split 256 cols.
__global__ __launch_bounds__(256) void wo_res_ln(
    const u16* __restrict__ A, const u16* __restrict__ Wt,
    float* __restrict__ x, u16* __restrict__ xb,
    const float* __restrict__ g, const float* __restrict__ b) {
  __shared__ float redS[64][4];
  __shared__ float redQ[64][4];
  int nwg = gridDim.x;  // 512
  int bid = blockIdx.x;
  int bm = ((bid & 7) * (nwg >> 3) + (bid >> 3)) * 64;

  int tid = threadIdx.x, lane = tid & 63, w = tid >> 6;
  int l15 = lane & 15, l4 = lane >> 4;

  const u16* Ab = A + (size_t)bm * 256;
  const u16* Wb = Wt + (size_t)(w * 64) * 256;

  f32x4 acc[4][4] = {};
#pragma unroll
  for (int kk = 0; kk < 8; ++kk) {
    f32x4 af[4], bf[4];
#pragma unroll
    for (int m = 0; m < 4; ++m)
      af[m] = *(const f32x4*)(Ab + (m * 16 + l15) * 256 + kk * 32 + l4 * 8);
#pragma unroll
    for (int n = 0; n < 4; ++n)
      bf[n] = *(const f32x4*)(Wb + (n * 16 + l15) * 256 + kk * 32 + l4 * 8);
#pragma unroll
    for (int m = 0; m < 4; ++m)
#pragma unroll
      for (int n = 0; n < 4; ++n) mfma16(acc[m][n], bf[n], af[m]);
  }
  MFMA_FENCE();

  // residual add + row stats
#pragma unroll
  for (int m = 0; m < 4; ++m) {
    int r = m * 16 + l15;
    float s = 0.f, q = 0.f;
#pragma unroll
    for (int n = 0; n < 4; ++n) {
      f32x4 xv = *(const f32x4*)(x + (size_t)(bm + r) * DMODEL + w * 64 + n * 16 + l4 * 4);
      f32x4 v = acc[m][n] + xv;
      acc[m][n] = v;
      s += v[0] + v[1] + v[2] + v[3];
      q += v[0] * v[0] + v[1] * v[1] + v[2] * v[2] + v[3] * v[3];
    }
    s += __shfl_xor(s, 16, 64);
    s += __shfl_xor(s, 32, 64);
    q += __shfl_xor(q, 16, 64);
    q += __shfl_xor(q, 32, 64);
    if (l4 == 0) {
      redS[r][w] = s;
      redQ[r][w] = q;
    }
  }
  __syncthreads();

  f32x4 gv[4], bv[4];
#pragma unroll
  for (int n = 0; n < 4; ++n) {
    gv[n] = *(const f32x4*)(g + w * 64 + n * 16 + l4 * 4);
    bv[n] = *(const f32x4*)(b + w * 64 + n * 16 + l4 * 4);
  }
#pragma unroll
  for (int m = 0; m < 4; ++m) {
    int r = m * 16 + l15;
    f32x4 sv = *(const f32x4*)redS[r];
    f32x4 qv = *(const f32x4*)redQ[r];
    float ssum = sv[0] + sv[1] + sv[2] + sv[3];
    float qsum = qv[0] + qv[1] + qv[2] + qv[3];
    float mean = ssum * (1.0f / DMODEL);
    float var = qsum * (1.0f / DMODEL) - mean * mean;
    float rs = rsqrtf(var + 1e-5f);
#pragma unroll
    for (int n = 0; n < 4; ++n) {
      f32x4 v = acc[m][n];
      *(f32x4*)(x + (size_t)(bm + r) * DMODEL + w * 64 + n * 16 + l4 * 4) = v;
      u16x4 o;
#pragma unroll
      for (int j = 0; j < 4; ++j)
        o[j] = f2bf((v[j] - mean) * rs * gv[n][j] + bv[n][j]);
      *(u16x4*)(xb + (size_t)(bm + r) * DMODEL + w * 64 + n * 16 + l4 * 4) = o;
    }
  }
}

// ------------------------------------------------------------ fused FFN ----
// x += gelu(xb @ W1^T + b1) @ W2^T + b2 ; xb = LN(x) (if DO_LN)
// 64 rows/block, 4 waves. H staged per 128-ff tile in LDS (bf16).
#define HST 152  // Hs row stride in u16 (304 B = 76 dw == 12 banks/row)
template <bool DO_LN>
__global__ __launch_bounds__(256) void ffn_fused(
    const u16* __restrict__ xbin, const u16* __restrict__ W1t,
    const u16* __restrict__ W2t, const float* __restrict__ b1,
    const float* __restrict__ b2, float* __restrict__ x,
    u16* __restrict__ xbout, const float* __restrict__ g,
    const float* __restrict__ b) {
  __shared__ u16 Hs[64 * HST];
  __shared__ float redS[64][4];
  __shared__ float redQ[64][4];

  int nwg = gridDim.x;  // 512
  int bid = blockIdx.x;
  int bm = ((bid & 7) * (nwg >> 3) + (bid >> 3)) * 64;

  int tid = threadIdx.x, lane = tid & 63, w = tid >> 6;
  int l15 = lane & 15, l4 = lane >> 4;

  // persistent row fragments: wave w owns rows w*16..w*16+15 for H production
  f32x4 xf[8];
#pragma unroll
  for (int kk = 0; kk < 8; ++kk)
    xf[kk] = *(const f32x4*)(xbin + (size_t)(bm + w * 16 + l15) * 256 + kk * 32 + l4 * 8);

  f32x4 acc[4][4] = {};

  for (int ft = 0; ft < 8; ++ft) {  // 128 ff per tile
    // ---- first GEMM: H[64 rows][128 ff] for this tile, row-split by wave --
#pragma unroll
    for (int h2 = 0; h2 < 2; ++h2) {
      f32x4 hacc[4] = {};
#pragma unroll
      for (int kk = 0; kk < 8; ++kk) {
#pragma unroll
        for (int nf = 0; nf < 4; ++nf) {
          f32x4 w1f = *(const f32x4*)(
              W1t + (size_t)(ft * 128 + h2 * 64 + nf * 16 + l15) * 256 + kk * 32 + l4 * 8);
          mfma16(hacc[nf], w1f, xf[kk]);
        }
      }
      MFMA_FENCE();
#pragma unroll
      for (int nf = 0; nf < 4; ++nf) {
        int ffb = ft * 128 + h2 * 64 + nf * 16 + l4 * 4;
        f32x4 b1v = *(const f32x4*)(b1 + ffb);
        u16x4 hv;
#pragma unroll
        for (int j = 0; j < 4; ++j) hv[j] = f2bf(gelu_f(hacc[nf][j] + b1v[j]));
        *(u16x4*)(Hs + (w * 16 + l15) * HST + h2 * 64 + nf * 16 + l4 * 4) = hv;
      }
    }
    __syncthreads();
    // ---- second GEMM: acc += H_tile @ W2_tile, col-split by wave ----------
#pragma unroll
    for (int kk2 = 0; kk2 < 4; ++kk2) {
      f32x4 af2[4], bf2[4];
#pragma unroll
      for (int m = 0; m < 4; ++m)
        af2[m] = *(const f32x4*)(Hs + (m * 16 + l15) * HST + kk2 * 32 + l4 * 8);
#pragma unroll
      for (int n = 0; n < 4; ++n)
        bf2[n] = *(const f32x4*)(
            W2t + (size_t)(w * 64 + n * 16 + l15) * 1024 + ft * 128 + kk2 * 32 + l4 * 8);
#pragma unroll
      for (int m = 0; m < 4; ++m)
#pragma unroll
        for (int n = 0; n < 4; ++n) mfma16(acc[m][n], bf2[n], af2[m]);
    }
    __syncthreads();  // Hs reused next ft
  }
  MFMA_FENCE();

  // ---- epilogue: + b2 + residual, then LN --------------------------------
  f32x4 b2v[4];
#pragma unroll
  for (int n = 0; n < 4; ++n)
    b2v[n] = *(const f32x4*)(b2 + w * 64 + n * 16 + l4 * 4);

#pragma unroll
  for (int m = 0; m < 4; ++m) {
    int r = m * 16 + l15;
    float s = 0.f, q = 0.f;
#pragma unroll
    for (int n = 0; n < 4; ++n) {
      f32x4 xv = *(const f32x4*)(x + (size_t)(bm + r) * DMODEL + w * 64 + n * 16 + l4 * 4);
      f32x4 v = acc[m][n] + b2v[n] + xv;
      acc[m][n] = v;
      s += v[0] + v[1] + v[2] + v[3];
      q += v[0] * v[0] + v[1] * v[1] + v[2] * v[2] + v[3] * v[3];
    }
    if (DO_LN) {
      s += __shfl_xor(s, 16, 64);
      s += __shfl_xor(s, 32, 64);
      q += __shfl_xor(q, 16, 64);
      q += __shfl_xor(q, 32, 64);
      if (l4 == 0) {
        redS[r][w] = s;
        redQ[r][w] = q;
      }
    }
  }
  if (DO_LN) __syncthreads();

  f32x4 gv[4], bv[4];
  if (DO_LN) {
#pragma unroll
    for (int n = 0; n < 4; ++n) {
      gv[n] = *(const f32x4*)(g + w * 64 + n * 16 + l4 * 4);
      bv[n] = *(const f32x4*)(b + w * 64 + n * 16 + l4 * 4);
    }
  }
#pragma unroll
  for (int m = 0; m < 4; ++m) {
    int r = m * 16 + l15;
    float mean = 0.f, rs = 0.f;
    if (DO_LN) {
      f32x4 sv = *(const f32x4*)redS[r];
      f32x4 qv = *(const f32x4*)redQ[r];
      float ssum = sv[0] + sv[1] + sv[2] + sv[3];
      float qsum = qv[0] + qv[1] + qv[2] + qv[3];
      mean = ssum * (1.0f / DMODEL);
      float var = qsum * (1.0f / DMODEL) - mean * mean;
      rs = rsqrtf(var + 1e-5f);
    }
#pragma unroll
    for (int n = 0; n < 4; ++n) {
      f32x4 v = acc[m][n];
      *(f32x4*)(x + (size_t)(bm + r) * DMODEL + w * 64 + n * 16 + l4 * 4) = v;
      if (DO_LN) {
        u16x4 o;
#pragma unroll
        for (int j = 0; j < 4; ++j)
          o[j] = f2bf((v[j] - mean) * rs * gv[n][j] + bv[n][j]);
        *(u16x4*)(xbout + (size_t)(bm + r) * DMODEL + w * 64 + n * 16 + l4 * 4) = o;
      }
    }
  }
}

// ------------------------------------------------------------ attention ----
__global__ __launch_bounds__(256) void attn_kernel(
    const u16* __restrict__ qkv, const int* __restrict__ amask,
    u16* __restrict__ ao) {
  int win = blockIdx.x, h = blockIdx.y, b = blockIdx.z;
  int tid = threadIdx.x, lane = tid & 63, wid = tid >> 6;
  int l15 = lane & 15, l4 = lane >> 4;

  __shared__ u16 Ks[192 * 32];
  __shared__ u16 Vts[32 * 200];
  __shared__ u16 Ps[64 * 200];
  __shared__ unsigned char valid[192];

  int t0 = win * WIN - WIN;

  if (tid < 192) {
    int t = t0 + tid;
    valid[tid] = (t >= 0 && t < S_LEN && amask[b * S_LEN + t] != 0) ? 1 : 0;
  }
#pragma unroll
  for (int c = 0; c < 3; ++c) {
    int chunk = c * 256 + tid;
    int key = chunk >> 2, kc = chunk & 3;
    int t = t0 + key;
    t = t < 0 ? 0 : (t >= S_LEN ? S_LEN - 1 : t);
    const u16* gp = qkv + (size_t)(b * S_LEN + t) * 768 + 256 + h * 32 + kc * 8;
    gload_lds16(gp, (char*)Ks + c * 4096 + wid * 1024);
  }
  for (int e = tid; e < 192 * 32; e += 256) {
    int key = e >> 5, d = e & 31;
    int t = t0 + key;
    t = t < 0 ? 0 : (t >= S_LEN ? S_LEN - 1 : t);
    Vts[d * 200 + key] = qkv[(size_t)(b * S_LEN + t) * 768 + 512 + h * 32 + d];
  }
  __syncthreads();

  int qrow = b * S_LEN + win * WIN + wid * 16 + l15;
  f32x4 aq = *(const f32x4*)(qkv + (size_t)qrow * 768 + h * 32 + l4 * 8);

  f32x4 sacc[12] = {};
#pragma unroll
  for (int f = 0; f < 12; ++f) {
    f32x4 bk = *(const f32x4*)(Ks + (f * 16 + l15) * 32 + l4 * 8);
    mfma16(sacc[f], aq, bk);
  }
  MFMA_FENCE();

  const float scale = 0.17677669529663687f;
  float mrow[4] = {-1e30f, -1e30f, -1e30f, -1e30f};
#pragma unroll
  for (int f = 0; f < 12; ++f) {
    bool ok = valid[f * 16 + l15] != 0;
#pragma unroll
    for (int j = 0; j < 4; ++j) {
      float sv = ok ? sacc[f][j] * scale : -1e9f;
      sacc[f][j] = sv;
      mrow[j] = fmaxf(mrow[j], sv);
    }
  }
#pragma unroll
  for (int j = 0; j < 4; ++j)
#pragma unroll
    for (int off = 1; off < 16; off <<= 1)
      mrow[j] = fmaxf(mrow[j], __shfl_xor(mrow[j], off, 64));

  float ssum[4] = {0.f, 0.f, 0.f, 0.f};
#pragma unroll
  for (int f = 0; f < 12; ++f)
#pragma unroll
    for (int j = 0; j < 4; ++j) {
      float p = __expf(sacc[f][j] - mrow[j]);
      sacc[f][j] = p;
      ssum[j] += p;
    }
#pragma unroll
  for (int j = 0; j < 4; ++j)
#pragma unroll
    for (int off = 1; off < 16; off <<= 1)
      ssum[j] += __shfl_xor(ssum[j], off, 64);

#pragma unroll
  for (int f = 0; f < 12; ++f)
#pragma unroll
    for (int j = 0; j < 4; ++j)
      Ps[(wid * 16 + l4 * 4 + j) * 200 + f * 16 + l15] = f2bf(sacc[f][j]);
  __syncthreads();

  f32x4 oacc[2] = {};
#pragma unroll
  for (int kk = 0; kk < 6; ++kk) {
    f32x4 ap = *(const f32x4*)(Ps + (wid * 16 + l15) * 200 + kk * 32 + l4 * 8);
#pragma unroll
    for (int nf = 0; nf < 2; ++nf) {
      f32x4 bv = *(const f32x4*)(Vts + (nf * 16 + l15) * 200 + kk * 32 + l4 * 8);
      mfma16(oacc[nf], ap, bv);
    }
  }
  MFMA_FENCE();

  float inv[4];
#pragma unroll
  for (int j = 0; j < 4; ++j) inv[j] = 1.0f / ssum[j];
#pragma unroll
  for (int nf = 0; nf < 2; ++nf)
#pragma unroll
    for (int j = 0; j < 4; ++j) {
      int orow = b * S_LEN + win * WIN + wid * 16 + l4 * 4 + j;
      ao[(size_t)orow * 256 + h * 32 + nf * 16 + l15] = f2bf(oacc[nf][j] * inv[j]);
    }
}

// ------------------------------------------------------------- scan --------
__global__ __launch_bounds__(256) void scan_kernel(const int* __restrict__ wsrt,
                                                   int* __restrict__ tgt) {
  __shared__ int part[256];
  int b = blockIdx.x, tid = threadIdx.x;
  const int* src = wsrt + b * S_LEN;
  int* dst = tgt + b * S_LEN;
  int base = tid * 32;
  int loc[32];
  int s = 0;
#pragma unroll
  for (int i = 0; i < 32; ++i) {
    loc[i] = src[base + i];
    s += loc[i];
  }
  part[tid] = s;
  __syncthreads();
  for (int off = 1; off < 256; off <<= 1) {
    int v = (tid >= off) ? part[tid - off] : 0;
    __syncthreads();
    part[tid] += v;
    __syncthreads();
  }
  int cum = part[tid] - s;
#pragma unroll
  for (int i = 0; i < 32; ++i) {
    cum += loc[i];
    dst[base + i] = (loc[i] > 0) ? (cum - 1) : -1;
  }
}

// ------------------------------------------------- final LN + gather -------
__global__ __launch_bounds__(64) void gather_ln_kernel(
    const float* __restrict__ x, const int* __restrict__ tgt,
    const float* __restrict__ g, const float* __restrict__ b,
    float* __restrict__ out) {
  int r = blockIdx.x;
  int tg = tgt[r];
  if (tg < 0) return;
  int bIdx = r >> 13;
  int lane = threadIdx.x;
  f32x4 v = *(const f32x4*)(x + (size_t)r * DMODEL + lane * 4);
  float s = v[0] + v[1] + v[2] + v[3];
  float q = v[0] * v[0] + v[1] * v[1] + v[2] * v[2] + v[3] * v[3];
  for (int off = 32; off; off >>= 1) {
    s += __shfl_xor(s, off, 64);
    q += __shfl_xor(q, off, 64);
  }
  float mean = s * (1.0f / DMODEL);
  float var = q * (1.0f / DMODEL) - mean * mean;
  float rs = rsqrtf(var + 1e-5f);
  f32x4 gg = *(const f32x4*)(g + lane * 4);
  f32x4 bb = *(const f32x4*)(b + lane * 4);
  f32x4 o;
  for (int j = 0; j < 4; ++j) o[j] = (v[j] - mean) * rs * gg[j] + bb[j];
  *(f32x4*)(out + (size_t)(bIdx * S_LEN + tg) * DMODEL + lane * 4) = o;
}

// ---------------------------------------------------------------------------
extern "C" void kernel_launch(void* const* d_in, const int* in_sizes, int n_in,
                              void* d_out, int out_size, void* d_ws,
                              size_t ws_size, hipStream_t stream) {
  const int* ids = (const int*)d_in[0];
  const int* amask = (const int*)d_in[1];
  const int* wstart = (const int*)d_in[2];
  const float* emb = (const float*)d_in[3];
  const float* pos = (const float*)d_in[4];
  const float* ln1g = (const float*)d_in[5];
  const float* ln1b = (const float*)d_in[6];
  const float* wq = (const float*)d_in[7];
  const float* wk = (const float*)d_in[8];
  const float* wv = (const float*)d_in[9];
  const float* wo = (const float*)d_in[10];
  const float* ln2g = (const float*)d_in[11];
  const float* ln2b = (const float*)d_in[12];
  const float* w1 = (const float*)d_in[13];
  const float* b1 = (const float*)d_in[14];
  const float* w2 = (const float*)d_in[15];
  const float* b2 = (const float*)d_in[16];
  const float* lnfg = (const float*)d_in[17];
  const float* lnfb = (const float*)d_in[18];

  char* ws = (char*)d_ws;
  const size_t OFF_X = 0;              // f32 [32768][256]
  const size_t OFF_XB = 33554432;      // bf16 [32768][256]
  const size_t OFF_AO = 50331648;      // bf16 [32768][256]
  const size_t OFF_BIG = 67108864;     // bf16 qkv [32768][768]
  const size_t OFF_WQKVT = 134217728;  // bf16 [6][768][256]
  const size_t OFF_WOT = 136577024;    // bf16 [6][256][256]
  const size_t OFF_W1T = 137363456;    // bf16 [6][1024][256]
  const size_t OFF_W2T = 140509184;    // bf16 [6][256][1024]
  const size_t OFF_TGT = 143654912;    // int [32768]
  const size_t NEEDED = 143785984;
  if (ws_size < NEEDED) return;

  float* x = (float*)(ws + OFF_X);
  u16* xb = (u16*)(ws + OFF_XB);
  u16* ao = (u16*)(ws + OFF_AO);
  u16* big = (u16*)(ws + OFF_BIG);
  u16* WqkvT = (u16*)(ws + OFF_WQKVT);
  u16* WoT = (u16*)(ws + OFF_WOT);
  u16* W1T = (u16*)(ws + OFF_W1T);
  u16* W2T = (u16*)(ws + OFF_W2T);
  int* tgt = (int*)(ws + OFF_TGT);

  tcast_kernel<<<1024, 256, 0, stream>>>(wq, WqkvT, NLAYER * 256 * 256, 256, 256, 768 * 256, 0);
  tcast_kernel<<<1024, 256, 0, stream>>>(wk, WqkvT, NLAYER * 256 * 256, 256, 256, 768 * 256, 256);
  tcast_kernel<<<1024, 256, 0, stream>>>(wv, WqkvT, NLAYER * 256 * 256, 256, 256, 768 * 256, 512);
  tcast_kernel<<<1024, 256, 0, stream>>>(wo, WoT, NLAYER * 256 * 256, 256, 256, 256 * 256, 0);
  tcast_kernel<<<2048, 256, 0, stream>>>(w1, W1T, NLAYER * 256 * 1024, 256, 1024, 1024 * 256, 0);
  tcast_kernel<<<2048, 256, 0, stream>>>(w2, W2T, NLAYER * 1024 * 256, 1024, 256, 256 * 1024, 0);

  embed_ln_kernel<<<MROWS / 4, 256, 0, stream>>>(ids, emb, pos, ln1g, ln1b, x, xb);
  zero_kernel<<<2048, 256, 0, stream>>>((float*)d_out, out_size / 4);
  scan_kernel<<<BATCH, 256, 0, stream>>>(wstart, tgt);

  for (int l = 0; l < NLAYER; ++l) {
    qkv_gemm<<<1536, 256, 0, stream>>>(xb, WqkvT + (size_t)l * 768 * 256, big);
    attn_kernel<<<dim3(NWIN, NHEAD, BATCH), 256, 0, stream>>>(big, amask, ao);
    wo_res_ln<<<512, 256, 0, stream>>>(ao, WoT + (size_t)l * 256 * 256, x, xb,
                                       ln2g + l * DMODEL, ln2b + l * DMODEL);
    if (l < NLAYER - 1) {
      ffn_fused<true><<<512, 256, 0, stream>>>(
          xb, W1T + (size_t)l * 1024 * 256, W2T + (size_t)l * 256 * 1024,
          b1 + l * FFDIM, b2 + l * DMODEL, x, xb,
          ln1g + (l + 1) * DMODEL, ln1b + (l + 1) * DMODEL);
    } else {
      ffn_fused<false><<<512, 256, 0, stream>>>(
          xb, W1T + (size_t)l * 1024 * 256, W2T + (size_t)l * 256 * 1024,
          b1 + l * FFDIM, b2 + l * DMODEL, x, nullptr, nullptr, nullptr);
    }
  }

  gather_ln_kernel<<<MROWS, 64, 0, stream>>>(x, tgt, lnfg, lnfb, (float*)d_out);
}

// Round 4
// 1038.081 us; speedup vs baseline: 1.8496x; 1.8496x over previous
//
#include <hip/hip_runtime.h>

// ---------------------------------------------------------------------------
// WordEncoder round 4: round-2 staged-LDS GEMM structure (known good) +
// swapped-operand vectorized epilogues, cvt_pk bf16 stores, cheap gelu.
// ---------------------------------------------------------------------------

#define S_LEN 8192
#define BATCH 4
#define DMODEL 256
#define NHEAD 8
#define WIN 64
#define NWIN 128
#define NLAYER 6
#define FFDIM 1024
#define MROWS (BATCH * S_LEN)

typedef float __attribute__((ext_vector_type(4))) f32x4;
typedef unsigned int __attribute__((ext_vector_type(2))) u32x2;
typedef unsigned short u16;
typedef unsigned short __attribute__((ext_vector_type(4))) u16x4;

__device__ __forceinline__ u16 f2bf(float f) {
  unsigned u = __builtin_bit_cast(unsigned, f);
  u += 0x7fffu + ((u >> 16) & 1u);
  return (u16)(u >> 16);
}

// packed f32->bf16 (RNE), 2 elems / instruction
__device__ __forceinline__ unsigned cvt_pk_bf16(float lo, float hi) {
  unsigned r;
  asm("v_cvt_pk_bf16_f32 %0, %1, %2" : "=v"(r) : "v"(lo), "v"(hi));
  return r;
}
__device__ __forceinline__ u32x2 pack_bf16x4(f32x4 v) {
  u32x2 o;
  o[0] = cvt_pk_bf16(v[0], v[1]);
  o[1] = cvt_pk_bf16(v[2], v[3]);
  return o;
}

// mfma16(d, P, Q): lane holds D[row from P's l15-space][col from Q's l15-space]
// With P = B-col fragment, Q = A-row fragment: lane = C[row=l15][cols=l4*4+j].
__device__ __forceinline__ void mfma16(f32x4& d, f32x4 a, f32x4 b) {
  asm volatile("v_mfma_f32_16x16x32_bf16 %0, %1, %2, %0"
               : "+v"(d) : "v"(a), "v"(b));
}
#define MFMA_FENCE() asm volatile("s_nop 7\n\ts_nop 7")

__device__ __forceinline__ void gload_lds16(const void* g, void* l) {
  __builtin_amdgcn_global_load_lds(
      (__attribute__((address_space(1))) void*)g,
      (__attribute__((address_space(3))) void*)l, 16, 0, 0);
}

// gelu (tanh approx) via sigmoid identity: 0.5t(1+tanh(u)) == t*sigmoid(2u)
__device__ __forceinline__ float gelu_f(float t) {
  float u = 0.7978845608028654f * (t + 0.044715f * t * t * t);
  float e = __expf(-2.0f * u);
  return t * __builtin_amdgcn_rcpf(1.0f + e);
}

// -------------------------------------------------- embed + LN1(layer 0) ---
__global__ __launch_bounds__(256) void embed_ln_kernel(
    const int* __restrict__ ids, const float* __restrict__ emb,
    const float* __restrict__ pos, const float* __restrict__ g,
    const float* __restrict__ b, float* __restrict__ x, u16* __restrict__ xb) {
  int wid = threadIdx.x >> 6, lane = threadIdx.x & 63;
  int r = blockIdx.x * 4 + wid;
  int s = r & (S_LEN - 1);
  int id = ids[r];
  f32x4 e = *(const f32x4*)(emb + (size_t)id * DMODEL + lane * 4);
  f32x4 p = *(const f32x4*)(pos + (size_t)s * DMODEL + lane * 4);
  f32x4 v = e + p;
  *(f32x4*)(x + (size_t)r * DMODEL + lane * 4) = v;
  float sm = v[0] + v[1] + v[2] + v[3];
  float q = v[0] * v[0] + v[1] * v[1] + v[2] * v[2] + v[3] * v[3];
  for (int off = 32; off; off >>= 1) {
    sm += __shfl_xor(sm, off, 64);
    q += __shfl_xor(q, off, 64);
  }
  float mean = sm * (1.0f / DMODEL);
  float var = q * (1.0f / DMODEL) - mean * mean;
  float rs = rsqrtf(var + 1e-5f);
  f32x4 gg = *(const f32x4*)(g + lane * 4);
  f32x4 bb = *(const f32x4*)(b + lane * 4);
  f32x4 o;
  for (int j = 0; j < 4; ++j) o[j] = (v[j] - mean) * rs * gg[j] + bb[j];
  *(u32x2*)(xb + (size_t)r * DMODEL + lane * 4) = pack_bf16x4(o);
}

// ----------------------------------------------------------------- zero ----
__global__ void zero_kernel(float* __restrict__ p, int n4) {
  int i = blockIdx.x * blockDim.x + threadIdx.x;
  int stride = gridDim.x * blockDim.x;
  f32x4 z = {0.f, 0.f, 0.f, 0.f};
  for (; i < n4; i += stride) ((f32x4*)p)[i] = z;
}

// ------------------------------------------------- weight transpose+cast ---
__global__ void tcast_kernel(const float* __restrict__ src, u16* __restrict__ dst,
                             int total, int K, int N, int dls, int rowOff) {
  int i = blockIdx.x * blockDim.x + threadIdx.x;
  int stride = gridDim.x * blockDim.x;
  int KN = K * N;
  for (; i < total; i += stride) {
    int l = i / KN;
    int rem = i - l * KN;
    int k = rem / N;
    int n = rem - k * N;
    dst[l * dls + (rowOff + n) * K + k] = f2bf(src[i]);
  }
}

// ------------------------------------------------------ plain GEMM (bf16) --
// C[M][N] = A[M][K] @ Bt[N][K]^T (+bias)(gelu). 128x128 tile, 4 waves (2x2),
// BK=64, XOR-swizzled LDS staging via global_load_lds, direct u16x4 stores.
template <bool GELU_ACT, bool HAS_BIAS>
__global__ __launch_bounds__(256) void gemm_bf16(
    const u16* __restrict__ A, const u16* __restrict__ Bt,
    u16* __restrict__ C, const float* __restrict__ bias,
    int N, int K, int nx) {
  __shared__ u16 As[128 * 64];
  __shared__ u16 Bs[128 * 64];

  int nwg = gridDim.x;
  int bid = blockIdx.x;
  int w8 = (bid & 7) * (nwg >> 3) + (bid >> 3);
  int cx = w8 % nx, ry = w8 / nx;
  int bm = ry * 128, bn = cx * 128;

  int tid = threadIdx.x, lane = tid & 63, wid = tid >> 6;
  int l15 = lane & 15, l4 = lane >> 4;
  int wm = wid >> 1, wn = wid & 1;

  const u16* Ab = A + (size_t)bm * K;
  const u16* Bb = Bt + (size_t)bn * K;

  f32x4 acc[4][4] = {};

  for (int kt = 0; kt < K; kt += 64) {
#pragma unroll
    for (int i = 0; i < 4; ++i) {
      int s = tid + i * 256;
      int r = s >> 3, c = (s & 7) ^ (r & 7);
      gload_lds16(Ab + (size_t)r * K + kt + c * 8,
                  (char*)As + (wid * 64 + i * 256) * 16);
    }
#pragma unroll
    for (int i = 0; i < 4; ++i) {
      int s = tid + i * 256;
      int r = s >> 3, c = (s & 7) ^ (r & 7);
      gload_lds16(Bb + (size_t)r * K + kt + c * 8,
                  (char*)Bs + (wid * 64 + i * 256) * 16);
    }
    __syncthreads();
#pragma unroll
    for (int t = 0; t < 2; ++t) {
      f32x4 af[4], bf[4];
#pragma unroll
      for (int m = 0; m < 4; ++m) {
        int r = wm * 64 + m * 16 + l15;
        af[m] = ((const f32x4*)As)[r * 8 + ((t * 4 + l4) ^ (r & 7))];
      }
#pragma unroll
      for (int n = 0; n < 4; ++n) {
        int r = wn * 64 + n * 16 + l15;
        bf[n] = ((const f32x4*)Bs)[r * 8 + ((t * 4 + l4) ^ (r & 7))];
      }
#pragma unroll
      for (int m = 0; m < 4; ++m)
#pragma unroll
        for (int n = 0; n < 4; ++n) mfma16(acc[m][n], bf[n], af[m]);
    }
    __syncthreads();
  }
  MFMA_FENCE();

  // epilogue: lane holds C[row = bm+wm*64+m*16+l15][cols = bn+wn*64+n*16+l4*4+j]
  int colB = bn + wn * 64;
  f32x4 bv[4];
#pragma unroll
  for (int n = 0; n < 4; ++n)
    bv[n] = HAS_BIAS ? *(const f32x4*)(bias + colB + n * 16 + l4 * 4)
                     : (f32x4){0.f, 0.f, 0.f, 0.f};
#pragma unroll
  for (int m = 0; m < 4; ++m) {
    int row = bm + wm * 64 + m * 16 + l15;
#pragma unroll
    for (int n = 0; n < 4; ++n) {
      f32x4 v = acc[m][n] + bv[n];
      if (GELU_ACT) {
#pragma unroll
        for (int j = 0; j < 4; ++j) v[j] = gelu_f(v[j]);
      }
      *(u32x2*)(C + (size_t)row * N + colB + n * 16 + l4 * 4) = pack_bf16x4(v);
    }
  }
}

// ------------------------------------- GEMM + residual (+bias) + LN fused --
// x_new = x + A@Bt^T (+bias); xb = LN(x_new)*g+b (if DO_LN)
// BM=128, BN=256 (full N), 8 waves (2x4), BK=64, swizzled staged LDS.
template <bool DO_LN>
__global__ __launch_bounds__(512) void gemm_res_ln(
    const u16* __restrict__ A, const u16* __restrict__ Bt,
    float* __restrict__ x, u16* __restrict__ xb,
    const float* __restrict__ bias, const float* __restrict__ g,
    const float* __restrict__ b, int K) {
  __shared__ u16 As[128 * 64];
  __shared__ u16 Bs[256 * 64];
  __shared__ float redS[128][4];
  __shared__ float redQ[128][4];

  int nwg = gridDim.x;
  int bid = blockIdx.x;
  int bm = ((bid & 7) * (nwg >> 3) + (bid >> 3)) * 128;

  int tid = threadIdx.x, lane = tid & 63, wid = tid >> 6;
  int l15 = lane & 15, l4 = lane >> 4;
  int wm = wid >> 2, wn = wid & 3;

  const u16* Ab = A + (size_t)bm * K;
  f32x4 acc[4][4] = {};

  for (int kt = 0; kt < K; kt += 64) {
#pragma unroll
    for (int i = 0; i < 2; ++i) {
      int s = tid + i * 512;
      int r = s >> 3, c = (s & 7) ^ (r & 7);
      gload_lds16(Ab + (size_t)r * K + kt + c * 8,
                  (char*)As + (wid * 64 + i * 512) * 16);
    }
#pragma unroll
    for (int i = 0; i < 4; ++i) {
      int s = tid + i * 512;
      int r = s >> 3, c = (s & 7) ^ (r & 7);
      gload_lds16(Bt + (size_t)r * K + kt + c * 8,
                  (char*)Bs + (wid * 64 + i * 512) * 16);
    }
    __syncthreads();
#pragma unroll
    for (int t = 0; t < 2; ++t) {
      f32x4 af[4], bf[4];
#pragma unroll
      for (int m = 0; m < 4; ++m) {
        int r = wm * 64 + m * 16 + l15;
        af[m] = ((const f32x4*)As)[r * 8 + ((t * 4 + l4) ^ (r & 7))];
      }
#pragma unroll
      for (int n = 0; n < 4; ++n) {
        int r = wn * 64 + n * 16 + l15;
        bf[n] = ((const f32x4*)Bs)[r * 8 + ((t * 4 + l4) ^ (r & 7))];
      }
#pragma unroll
      for (int m = 0; m < 4; ++m)
#pragma unroll
        for (int n = 0; n < 4; ++n) mfma16(acc[m][n], bf[n], af[m]);
    }
    __syncthreads();
  }
  MFMA_FENCE();

  int colB = wn * 64;
  f32x4 bv[4];
#pragma unroll
  for (int n = 0; n < 4; ++n)
    bv[n] = bias ? *(const f32x4*)(bias + colB + n * 16 + l4 * 4)
                 : (f32x4){0.f, 0.f, 0.f, 0.f};

  // pass 1: bias + residual, row stats
#pragma unroll
  for (int m = 0; m < 4; ++m) {
    int r = wm * 64 + m * 16 + l15;
    size_t rowoff = (size_t)(bm + r) * DMODEL + colB;
    float s = 0.f, q = 0.f;
#pragma unroll
    for (int n = 0; n < 4; ++n) {
      f32x4 xv = *(const f32x4*)(x + rowoff + n * 16 + l4 * 4);
      f32x4 v = acc[m][n] + bv[n] + xv;
      acc[m][n] = v;
      s += v[0] + v[1] + v[2] + v[3];
      q += v[0] * v[0] + v[1] * v[1] + v[2] * v[2] + v[3] * v[3];
    }
    if (DO_LN) {
      s += __shfl_xor(s, 16, 64);
      s += __shfl_xor(s, 32, 64);
      q += __shfl_xor(q, 16, 64);
      q += __shfl_xor(q, 32, 64);
      if (l4 == 0) {
        redS[r][wn] = s;
        redQ[r][wn] = q;
      }
    }
  }
  if (DO_LN) __syncthreads();

  f32x4 gv[4], bbv[4];
  if (DO_LN) {
#pragma unroll
    for (int n = 0; n < 4; ++n) {
      gv[n] = *(const f32x4*)(g + colB + n * 16 + l4 * 4);
      bbv[n] = *(const f32x4*)(b + colB + n * 16 + l4 * 4);
    }
  }
#pragma unroll
  for (int m = 0; m < 4; ++m) {
    int r = wm * 64 + m * 16 + l15;
    size_t rowoff = (size_t)(bm + r) * DMODEL + colB;
    float mean = 0.f, rs = 0.f;
    if (DO_LN) {
      f32x4 sv = *(const f32x4*)redS[r];
      f32x4 qv = *(const f32x4*)redQ[r];
      float ssum = sv[0] + sv[1] + sv[2] + sv[3];
      float qsum = qv[0] + qv[1] + qv[2] + qv[3];
      mean = ssum * (1.0f / DMODEL);
      float var = qsum * (1.0f / DMODEL) - mean * mean;
      rs = rsqrtf(var + 1e-5f);
    }
#pragma unroll
    for (int n = 0; n < 4; ++n) {
      f32x4 v = acc[m][n];
      *(f32x4*)(x + rowoff + n * 16 + l4 * 4) = v;
      if (DO_LN) {
        f32x4 o;
#pragma unroll
        for (int j = 0; j < 4; ++j)
          o[j] = (v[j] - mean) * rs * gv[n][j] + bbv[n][j];
        *(u32x2*)(xb + rowoff + n * 16 + l4 * 4) = pack_bf16x4(o);
      }
    }
  }
}

// ------------------------------------------------------------ attention ----
__global__ __launch_bounds__(256) void attn_kernel(
    const u16* __restrict__ qkv, const int* __restrict__ amask,
    u16* __restrict__ ao) {
  int win = blockIdx.x, h = blockIdx.y, b = blockIdx.z;
  int tid = threadIdx.x, lane = tid & 63, wid = tid >> 6;
  int l15 = lane & 15, l4 = lane >> 4;

  __shared__ u16 Ks[192 * 32];
  __shared__ u16 Vts[32 * 200];
  __shared__ u16 Ps[64 * 200];
  __shared__ float invS[64];
  __shared__ unsigned char valid[192];

  int t0 = win * WIN - WIN;

  if (tid < 192) {
    int t = t0 + tid;
    valid[tid] = (t >= 0 && t < S_LEN && amask[b * S_LEN + t] != 0) ? 1 : 0;
  }
#pragma unroll
  for (int c = 0; c < 3; ++c) {
    int chunk = c * 256 + tid;
    int key = chunk >> 2, kc = chunk & 3;
    int t = t0 + key;
    t = t < 0 ? 0 : (t >= S_LEN ? S_LEN - 1 : t);
    const u16* gp = qkv + (size_t)(b * S_LEN + t) * 768 + 256 + h * 32 + kc * 8;
    gload_lds16(gp, (char*)Ks + c * 4096 + wid * 1024);
  }
  for (int e = tid; e < 192 * 32; e += 256) {
    int key = e >> 5, d = e & 31;
    int t = t0 + key;
    t = t < 0 ? 0 : (t >= S_LEN ? S_LEN - 1 : t);
    Vts[d * 200 + key] = qkv[(size_t)(b * S_LEN + t) * 768 + 512 + h * 32 + d];
  }
  __syncthreads();

  int qrow = b * S_LEN + win * WIN + wid * 16 + l15;
  f32x4 aq = *(const f32x4*)(qkv + (size_t)qrow * 768 + h * 32 + l4 * 8);

  // lane holds S[qrow = wid*16 + l4*4 + j][key = f*16 + l15]
  f32x4 sacc[12] = {};
#pragma unroll
  for (int f = 0; f < 12; ++f) {
    f32x4 bk = *(const f32x4*)(Ks + (f * 16 + l15) * 32 + l4 * 8);
    mfma16(sacc[f], aq, bk);
  }
  MFMA_FENCE();

  const float scale = 0.17677669529663687f;
  float mrow[4] = {-1e30f, -1e30f, -1e30f, -1e30f};
#pragma unroll
  for (int f = 0; f < 12; ++f) {
    bool ok = valid[f * 16 + l15] != 0;
#pragma unroll
    for (int j = 0; j < 4; ++j) {
      float sv = ok ? sacc[f][j] * scale : -1e9f;
      sacc[f][j] = sv;
      mrow[j] = fmaxf(mrow[j], sv);
    }
  }
#pragma unroll
  for (int j = 0; j < 4; ++j)
#pragma unroll
    for (int off = 1; off < 16; off <<= 1)
      mrow[j] = fmaxf(mrow[j], __shfl_xor(mrow[j], off, 64));

  float ssum[4] = {0.f, 0.f, 0.f, 0.f};
#pragma unroll
  for (int f = 0; f < 12; ++f)
#pragma unroll
    for (int j = 0; j < 4; ++j) {
      float p = __expf(sacc[f][j] - mrow[j]);
      sacc[f][j] = p;
      ssum[j] += p;
    }
#pragma unroll
  for (int j = 0; j < 4; ++j)
#pragma unroll
    for (int off = 1; off < 16; off <<= 1)
      ssum[j] += __shfl_xor(ssum[j], off, 64);

#pragma unroll
  for (int f = 0; f < 12; ++f)
#pragma unroll
    for (int j = 0; j < 4; ++j)
      Ps[(wid * 16 + l4 * 4 + j) * 200 + f * 16 + l15] = f2bf(sacc[f][j]);
  if (l15 == 0) {
#pragma unroll
    for (int j = 0; j < 4; ++j)
      invS[wid * 16 + l4 * 4 + j] = 1.0f / ssum[j];
  }
  __syncthreads();

  // PV swapped: lane holds O[qrow = wid*16 + l15][vcol = nf*16 + l4*4 + j]
  f32x4 oacc[2] = {};
#pragma unroll
  for (int kk = 0; kk < 6; ++kk) {
    f32x4 ap = *(const f32x4*)(Ps + (wid * 16 + l15) * 200 + kk * 32 + l4 * 8);
#pragma unroll
    for (int nf = 0; nf < 2; ++nf) {
      f32x4 bvv = *(const f32x4*)(Vts + (nf * 16 + l15) * 200 + kk * 32 + l4 * 8);
      mfma16(oacc[nf], bvv, ap);
    }
  }
  MFMA_FENCE();

  float invv = invS[wid * 16 + l15];
  int orow = b * S_LEN + win * WIN + wid * 16 + l15;
#pragma unroll
  for (int nf = 0; nf < 2; ++nf) {
    f32x4 v = oacc[nf] * invv;
    *(u32x2*)(ao + (size_t)orow * 256 + h * 32 + nf * 16 + l4 * 4) = pack_bf16x4(v);
  }
}

// ------------------------------------------------------------- scan --------
__global__ __launch_bounds__(256) void scan_kernel(const int* __restrict__ wsrt,
                                                   int* __restrict__ tgt) {
  __shared__ int part[256];
  int b = blockIdx.x, tid = threadIdx.x;
  const int* src = wsrt + b * S_LEN;
  int* dst = tgt + b * S_LEN;
  int base = tid * 32;
  int loc[32];
  int s = 0;
#pragma unroll
  for (int i = 0; i < 32; ++i) {
    loc[i] = src[base + i];
    s += loc[i];
  }
  part[tid] = s;
  __syncthreads();
  for (int off = 1; off < 256; off <<= 1) {
    int v = (tid >= off) ? part[tid - off] : 0;
    __syncthreads();
    part[tid] += v;
    __syncthreads();
  }
  int cum = part[tid] - s;
#pragma unroll
  for (int i = 0; i < 32; ++i) {
    cum += loc[i];
    dst[base + i] = (loc[i] > 0) ? (cum - 1) : -1;
  }
}

// ------------------------------------------------- final LN + gather -------
__global__ __launch_bounds__(64) void gather_ln_kernel(
    const float* __restrict__ x, const int* __restrict__ tgt,
    const float* __restrict__ g, const float* __restrict__ b,
    float* __restrict__ out) {
  int r = blockIdx.x;
  int tg = tgt[r];
  if (tg < 0) return;
  int bIdx = r >> 13;
  int lane = threadIdx.x;
  f32x4 v = *(const f32x4*)(x + (size_t)r * DMODEL + lane * 4);
  float s = v[0] + v[1] + v[2] + v[3];
  float q = v[0] * v[0] + v[1] * v[1] + v[2] * v[2] + v[3] * v[3];
  for (int off = 32; off; off >>= 1) {
    s += __shfl_xor(s, off, 64);
    q += __shfl_xor(q, off, 64);
  }
  float mean = s * (1.0f / DMODEL);
  float var = q * (1.0f / DMODEL) - mean * mean;
  float rs = rsqrtf(var + 1e-5f);
  f32x4 gg = *(const f32x4*)(g + lane * 4);
  f32x4 bb = *(const f32x4*)(b + lane * 4);
  f32x4 o;
  for (int j = 0; j < 4; ++j) o[j] = (v[j] - mean) * rs * gg[j] + bb[j];
  *(f32x4*)(out + (size_t)(bIdx * S_LEN + tg) * DMODEL + lane * 4) = o;
}

// ---------------------------------------------------------------------------
extern "C" void kernel_launch(void* const* d_in, const int* in_sizes, int n_in,
                              void* d_out, int out_size, void* d_ws,
                              size_t ws_size, hipStream_t stream) {
  const int* ids = (const int*)d_in[0];
  const int* amask = (const int*)d_in[1];
  const int* wstart = (const int*)d_in[2];
  const float* emb = (const float*)d_in[3];
  const float* pos = (const float*)d_in[4];
  const float* ln1g = (const float*)d_in[5];
  const float* ln1b = (const float*)d_in[6];
  const float* wq = (const float*)d_in[7];
  const float* wk = (const float*)d_in[8];
  const float* wv = (const float*)d_in[9];
  const float* wo = (const float*)d_in[10];
  const float* ln2g = (const float*)d_in[11];
  const float* ln2b = (const float*)d_in[12];
  const float* w1 = (const float*)d_in[13];
  const float* b1 = (const float*)d_in[14];
  const float* w2 = (const float*)d_in[15];
  const float* b2 = (const float*)d_in[16];
  const float* lnfg = (const float*)d_in[17];
  const float* lnfb = (const float*)d_in[18];

  char* ws = (char*)d_ws;
  const size_t OFF_X = 0;              // f32 [32768][256]
  const size_t OFF_XB = 33554432;      // bf16 [32768][256]
  const size_t OFF_AO = 50331648;      // bf16 [32768][256]
  const size_t OFF_BIG = 67108864;     // bf16 qkv [32768][768] / ffh [32768][1024]
  const size_t OFF_WQKVT = 134217728;  // bf16 [6][768][256]
  const size_t OFF_WOT = 136577024;    // bf16 [6][256][256]
  const size_t OFF_W1T = 137363456;    // bf16 [6][1024][256]
  const size_t OFF_W2T = 140509184;    // bf16 [6][256][1024]
  const size_t OFF_TGT = 143654912;    // int [32768]
  const size_t NEEDED = 143785984;
  if (ws_size < NEEDED) return;

  float* x = (float*)(ws + OFF_X);
  u16* xb = (u16*)(ws + OFF_XB);
  u16* ao = (u16*)(ws + OFF_AO);
  u16* big = (u16*)(ws + OFF_BIG);
  u16* WqkvT = (u16*)(ws + OFF_WQKVT);
  u16* WoT = (u16*)(ws + OFF_WOT);
  u16* W1T = (u16*)(ws + OFF_W1T);
  u16* W2T = (u16*)(ws + OFF_W2T);
  int* tgt = (int*)(ws + OFF_TGT);

  tcast_kernel<<<1024, 256, 0, stream>>>(wq, WqkvT, NLAYER * 256 * 256, 256, 256, 768 * 256, 0);
  tcast_kernel<<<1024, 256, 0, stream>>>(wk, WqkvT, NLAYER * 256 * 256, 256, 256, 768 * 256, 256);
  tcast_kernel<<<1024, 256, 0, stream>>>(wv, WqkvT, NLAYER * 256 * 256, 256, 256, 768 * 256, 512);
  tcast_kernel<<<1024, 256, 0, stream>>>(wo, WoT, NLAYER * 256 * 256, 256, 256, 256 * 256, 0);
  tcast_kernel<<<2048, 256, 0, stream>>>(w1, W1T, NLAYER * 256 * 1024, 256, 1024, 1024 * 256, 0);
  tcast_kernel<<<2048, 256, 0, stream>>>(w2, W2T, NLAYER * 1024 * 256, 1024, 256, 256 * 1024, 0);

  embed_ln_kernel<<<MROWS / 4, 256, 0, stream>>>(ids, emb, pos, ln1g, ln1b, x, xb);
  zero_kernel<<<2048, 256, 0, stream>>>((float*)d_out, out_size / 4);
  scan_kernel<<<BATCH, 256, 0, stream>>>(wstart, tgt);

  for (int l = 0; l < NLAYER; ++l) {
    // qkv = xb @ WqkvT[l]   (N=768, 1536 blocks)
    gemm_bf16<false, false><<<1536, 256, 0, stream>>>(
        xb, WqkvT + (size_t)l * 768 * 256, big, nullptr, 768, 256, 6);
    // attention
    attn_kernel<<<dim3(NWIN, NHEAD, BATCH), 256, 0, stream>>>(big, amask, ao);
    // x += ao @ WoT[l]; xb = LN2(x)
    gemm_res_ln<true><<<MROWS / 128, 512, 0, stream>>>(
        ao, WoT + (size_t)l * 256 * 256, x, xb, nullptr,
        ln2g + l * DMODEL, ln2b + l * DMODEL, 256);
    // ffh = gelu(xb @ W1T[l] + b1)   (N=1024, 2048 blocks)
    gemm_bf16<true, true><<<2048, 256, 0, stream>>>(
        xb, W1T + (size_t)l * 1024 * 256, big, b1 + l * FFDIM, 1024, 256, 8);
    // x += ffh @ W2T[l] + b2; xb = LN1[l+1](x)
    if (l < NLAYER - 1) {
      gemm_res_ln<true><<<MROWS / 128, 512, 0, stream>>>(
          big, W2T + (size_t)l * 256 * 1024, x, xb, b2 + l * DMODEL,
          ln1g + (l + 1) * DMODEL, ln1b + (l + 1) * DMODEL, 1024);
    } else {
      gemm_res_ln<false><<<MROWS / 128, 512, 0, stream>>>(
          big, W2T + (size_t)l * 256 * 1024, x, nullptr, b2 + l * DMODEL,
          nullptr, nullptr, 1024);
    }
  }

  gather_ln_kernel<<<MROWS, 64, 0, stream>>>(x, tgt, lnfg, lnfb, (float*)d_out);
}

// Round 5
// 979.407 us; speedup vs baseline: 1.9604x; 1.0599x over previous
//
#include <hip/hip_runtime.h>

// ---------------------------------------------------------------------------
// WordEncoder round 5: attention rewrite — swapped QK^T (lane-local softmax
// rows), conflict-free LDS strides, cvt_pk packed P, Ps/Ks union (4 blk/CU).
// GEMM path unchanged from round 4.
// ---------------------------------------------------------------------------

#define S_LEN 8192
#define BATCH 4
#define DMODEL 256
#define NHEAD 8
#define WIN 64
#define NWIN 128
#define NLAYER 6
#define FFDIM 1024
#define MROWS (BATCH * S_LEN)

typedef float __attribute__((ext_vector_type(4))) f32x4;
typedef unsigned int __attribute__((ext_vector_type(2))) u32x2;
typedef unsigned short u16;
typedef unsigned short __attribute__((ext_vector_type(4))) u16x4;

__device__ __forceinline__ u16 f2bf(float f) {
  unsigned u = __builtin_bit_cast(unsigned, f);
  u += 0x7fffu + ((u >> 16) & 1u);
  return (u16)(u >> 16);
}

__device__ __forceinline__ unsigned cvt_pk_bf16(float lo, float hi) {
  unsigned r;
  asm("v_cvt_pk_bf16_f32 %0, %1, %2" : "=v"(r) : "v"(lo), "v"(hi));
  return r;
}
__device__ __forceinline__ u32x2 pack_bf16x4(f32x4 v) {
  u32x2 o;
  o[0] = cvt_pk_bf16(v[0], v[1]);
  o[1] = cvt_pk_bf16(v[2], v[3]);
  return o;
}

// mfma16(d, arg1, arg2): lane holds D[row = arg2.l15-space][cols = arg1's
// l15-space at l4*4+j]  (validated via qkv_gemm round-3/4)
__device__ __forceinline__ void mfma16(f32x4& d, f32x4 a, f32x4 b) {
  asm volatile("v_mfma_f32_16x16x32_bf16 %0, %1, %2, %0"
               : "+v"(d) : "v"(a), "v"(b));
}
#define MFMA_FENCE() asm volatile("s_nop 7\n\ts_nop 7")

__device__ __forceinline__ void gload_lds16(const void* g, void* l) {
  __builtin_amdgcn_global_load_lds(
      (__attribute__((address_space(1))) void*)g,
      (__attribute__((address_space(3))) void*)l, 16, 0, 0);
}

__device__ __forceinline__ float gelu_f(float t) {
  float u = 0.7978845608028654f * (t + 0.044715f * t * t * t);
  float e = __expf(-2.0f * u);
  return t * __builtin_amdgcn_rcpf(1.0f + e);
}

// -------------------------------------------------- embed + LN1(layer 0) ---
__global__ __launch_bounds__(256) void embed_ln_kernel(
    const int* __restrict__ ids, const float* __restrict__ emb,
    const float* __restrict__ pos, const float* __restrict__ g,
    const float* __restrict__ b, float* __restrict__ x, u16* __restrict__ xb) {
  int wid = threadIdx.x >> 6, lane = threadIdx.x & 63;
  int r = blockIdx.x * 4 + wid;
  int s = r & (S_LEN - 1);
  int id = ids[r];
  f32x4 e = *(const f32x4*)(emb + (size_t)id * DMODEL + lane * 4);
  f32x4 p = *(const f32x4*)(pos + (size_t)s * DMODEL + lane * 4);
  f32x4 v = e + p;
  *(f32x4*)(x + (size_t)r * DMODEL + lane * 4) = v;
  float sm = v[0] + v[1] + v[2] + v[3];
  float q = v[0] * v[0] + v[1] * v[1] + v[2] * v[2] + v[3] * v[3];
  for (int off = 32; off; off >>= 1) {
    sm += __shfl_xor(sm, off, 64);
    q += __shfl_xor(q, off, 64);
  }
  float mean = sm * (1.0f / DMODEL);
  float var = q * (1.0f / DMODEL) - mean * mean;
  float rs = rsqrtf(var + 1e-5f);
  f32x4 gg = *(const f32x4*)(g + lane * 4);
  f32x4 bb = *(const f32x4*)(b + lane * 4);
  f32x4 o;
  for (int j = 0; j < 4; ++j) o[j] = (v[j] - mean) * rs * gg[j] + bb[j];
  *(u32x2*)(xb + (size_t)r * DMODEL + lane * 4) = pack_bf16x4(o);
}

// ----------------------------------------------------------------- zero ----
__global__ void zero_kernel(float* __restrict__ p, int n4) {
  int i = blockIdx.x * blockDim.x + threadIdx.x;
  int stride = gridDim.x * blockDim.x;
  f32x4 z = {0.f, 0.f, 0.f, 0.f};
  for (; i < n4; i += stride) ((f32x4*)p)[i] = z;
}

// ------------------------------------------------- weight transpose+cast ---
__global__ void tcast_kernel(const float* __restrict__ src, u16* __restrict__ dst,
                             int total, int K, int N, int dls, int rowOff) {
  int i = blockIdx.x * blockDim.x + threadIdx.x;
  int stride = gridDim.x * blockDim.x;
  int KN = K * N;
  for (; i < total; i += stride) {
    int l = i / KN;
    int rem = i - l * KN;
    int k = rem / N;
    int n = rem - k * N;
    dst[l * dls + (rowOff + n) * K + k] = f2bf(src[i]);
  }
}

// ------------------------------------------------------ plain GEMM (bf16) --
template <bool GELU_ACT, bool HAS_BIAS>
__global__ __launch_bounds__(256) void gemm_bf16(
    const u16* __restrict__ A, const u16* __restrict__ Bt,
    u16* __restrict__ C, const float* __restrict__ bias,
    int N, int K, int nx) {
  __shared__ u16 As[128 * 64];
  __shared__ u16 Bs[128 * 64];

  int nwg = gridDim.x;
  int bid = blockIdx.x;
  int w8 = (bid & 7) * (nwg >> 3) + (bid >> 3);
  int cx = w8 % nx, ry = w8 / nx;
  int bm = ry * 128, bn = cx * 128;

  int tid = threadIdx.x, lane = tid & 63, wid = tid >> 6;
  int l15 = lane & 15, l4 = lane >> 4;
  int wm = wid >> 1, wn = wid & 1;

  const u16* Ab = A + (size_t)bm * K;
  const u16* Bb = Bt + (size_t)bn * K;

  f32x4 acc[4][4] = {};

  for (int kt = 0; kt < K; kt += 64) {
#pragma unroll
    for (int i = 0; i < 4; ++i) {
      int s = tid + i * 256;
      int r = s >> 3, c = (s & 7) ^ (r & 7);
      gload_lds16(Ab + (size_t)r * K + kt + c * 8,
                  (char*)As + (wid * 64 + i * 256) * 16);
    }
#pragma unroll
    for (int i = 0; i < 4; ++i) {
      int s = tid + i * 256;
      int r = s >> 3, c = (s & 7) ^ (r & 7);
      gload_lds16(Bb + (size_t)r * K + kt + c * 8,
                  (char*)Bs + (wid * 64 + i * 256) * 16);
    }
    __syncthreads();
#pragma unroll
    for (int t = 0; t < 2; ++t) {
      f32x4 af[4], bf[4];
#pragma unroll
      for (int m = 0; m < 4; ++m) {
        int r = wm * 64 + m * 16 + l15;
        af[m] = ((const f32x4*)As)[r * 8 + ((t * 4 + l4) ^ (r & 7))];
      }
#pragma unroll
      for (int n = 0; n < 4; ++n) {
        int r = wn * 64 + n * 16 + l15;
        bf[n] = ((const f32x4*)Bs)[r * 8 + ((t * 4 + l4) ^ (r & 7))];
      }
#pragma unroll
      for (int m = 0; m < 4; ++m)
#pragma unroll
        for (int n = 0; n < 4; ++n) mfma16(acc[m][n], bf[n], af[m]);
    }
    __syncthreads();
  }
  MFMA_FENCE();

  int colB = bn + wn * 64;
  f32x4 bv[4];
#pragma unroll
  for (int n = 0; n < 4; ++n)
    bv[n] = HAS_BIAS ? *(const f32x4*)(bias + colB + n * 16 + l4 * 4)
                     : (f32x4){0.f, 0.f, 0.f, 0.f};
#pragma unroll
  for (int m = 0; m < 4; ++m) {
    int row = bm + wm * 64 + m * 16 + l15;
#pragma unroll
    for (int n = 0; n < 4; ++n) {
      f32x4 v = acc[m][n] + bv[n];
      if (GELU_ACT) {
#pragma unroll
        for (int j = 0; j < 4; ++j) v[j] = gelu_f(v[j]);
      }
      *(u32x2*)(C + (size_t)row * N + colB + n * 16 + l4 * 4) = pack_bf16x4(v);
    }
  }
}

// ------------------------------------- GEMM + residual (+bias) + LN fused --
template <bool DO_LN>
__global__ __launch_bounds__(512) void gemm_res_ln(
    const u16* __restrict__ A, const u16* __restrict__ Bt,
    float* __restrict__ x, u16* __restrict__ xb,
    const float* __restrict__ bias, const float* __restrict__ g,
    const float* __restrict__ b, int K) {
  __shared__ u16 As[128 * 64];
  __shared__ u16 Bs[256 * 64];
  __shared__ float redS[128][4];
  __shared__ float redQ[128][4];

  int nwg = gridDim.x;
  int bid = blockIdx.x;
  int bm = ((bid & 7) * (nwg >> 3) + (bid >> 3)) * 128;

  int tid = threadIdx.x, lane = tid & 63, wid = tid >> 6;
  int l15 = lane & 15, l4 = lane >> 4;
  int wm = wid >> 2, wn = wid & 3;

  const u16* Ab = A + (size_t)bm * K;
  f32x4 acc[4][4] = {};

  for (int kt = 0; kt < K; kt += 64) {
#pragma unroll
    for (int i = 0; i < 2; ++i) {
      int s = tid + i * 512;
      int r = s >> 3, c = (s & 7) ^ (r & 7);
      gload_lds16(Ab + (size_t)r * K + kt + c * 8,
                  (char*)As + (wid * 64 + i * 512) * 16);
    }
#pragma unroll
    for (int i = 0; i < 4; ++i) {
      int s = tid + i * 512;
      int r = s >> 3, c = (s & 7) ^ (r & 7);
      gload_lds16(Bt + (size_t)r * K + kt + c * 8,
                  (char*)Bs + (wid * 64 + i * 512) * 16);
    }
    __syncthreads();
#pragma unroll
    for (int t = 0; t < 2; ++t) {
      f32x4 af[4], bf[4];
#pragma unroll
      for (int m = 0; m < 4; ++m) {
        int r = wm * 64 + m * 16 + l15;
        af[m] = ((const f32x4*)As)[r * 8 + ((t * 4 + l4) ^ (r & 7))];
      }
#pragma unroll
      for (int n = 0; n < 4; ++n) {
        int r = wn * 64 + n * 16 + l15;
        bf[n] = ((const f32x4*)Bs)[r * 8 + ((t * 4 + l4) ^ (r & 7))];
      }
#pragma unroll
      for (int m = 0; m < 4; ++m)
#pragma unroll
        for (int n = 0; n < 4; ++n) mfma16(acc[m][n], bf[n], af[m]);
    }
    __syncthreads();
  }
  MFMA_FENCE();

  int colB = wn * 64;
  f32x4 bv[4];
#pragma unroll
  for (int n = 0; n < 4; ++n)
    bv[n] = bias ? *(const f32x4*)(bias + colB + n * 16 + l4 * 4)
                 : (f32x4){0.f, 0.f, 0.f, 0.f};

#pragma unroll
  for (int m = 0; m < 4; ++m) {
    int r = wm * 64 + m * 16 + l15;
    size_t rowoff = (size_t)(bm + r) * DMODEL + colB;
    float s = 0.f, q = 0.f;
#pragma unroll
    for (int n = 0; n < 4; ++n) {
      f32x4 xv = *(const f32x4*)(x + rowoff + n * 16 + l4 * 4);
      f32x4 v = acc[m][n] + bv[n] + xv;
      acc[m][n] = v;
      s += v[0] + v[1] + v[2] + v[3];
      q += v[0] * v[0] + v[1] * v[1] + v[2] * v[2] + v[3] * v[3];
    }
    if (DO_LN) {
      s += __shfl_xor(s, 16, 64);
      s += __shfl_xor(s, 32, 64);
      q += __shfl_xor(q, 16, 64);
      q += __shfl_xor(q, 32, 64);
      if (l4 == 0) {
        redS[r][wn] = s;
        redQ[r][wn] = q;
      }
    }
  }
  if (DO_LN) __syncthreads();

  f32x4 gv[4], bbv[4];
  if (DO_LN) {
#pragma unroll
    for (int n = 0; n < 4; ++n) {
      gv[n] = *(const f32x4*)(g + colB + n * 16 + l4 * 4);
      bbv[n] = *(const f32x4*)(b + colB + n * 16 + l4 * 4);
    }
  }
#pragma unroll
  for (int m = 0; m < 4; ++m) {
    int r = wm * 64 + m * 16 + l15;
    size_t rowoff = (size_t)(bm + r) * DMODEL + colB;
    float mean = 0.f, rs = 0.f;
    if (DO_LN) {
      f32x4 sv = *(const f32x4*)redS[r];
      f32x4 qv = *(const f32x4*)redQ[r];
      float ssum = sv[0] + sv[1] + sv[2] + sv[3];
      float qsum = qv[0] + qv[1] + qv[2] + qv[3];
      mean = ssum * (1.0f / DMODEL);
      float var = qsum * (1.0f / DMODEL) - mean * mean;
      rs = rsqrtf(var + 1e-5f);
    }
#pragma unroll
    for (int n = 0; n < 4; ++n) {
      f32x4 v = acc[m][n];
      *(f32x4*)(x + rowoff + n * 16 + l4 * 4) = v;
      if (DO_LN) {
        f32x4 o;
#pragma unroll
        for (int j = 0; j < 4; ++j)
          o[j] = (v[j] - mean) * rs * gv[n][j] + bbv[n][j];
        *(u32x2*)(xb + rowoff + n * 16 + l4 * 4) = pack_bf16x4(o);
      }
    }
  }
}

// ------------------------------------------------------------ attention ----
// Swapped QK^T: lane (l15,l4) holds S[qrow = wid*16+l15][keys f*16+l4*4+j].
// Softmax is lane-local + 2 shfl_xor. P packed via cvt_pk into Ps (union
// with Ks). PV: O[qrow=l15][vcol] with per-lane 1/sum.
// LDS strides: Ks 40 u16 (2-way), Ps 216 (2-way), Vts 200 (2-way reads).
__global__ __launch_bounds__(256, 4) void attn_kernel(
    const u16* __restrict__ qkv, const int* __restrict__ amask,
    u16* __restrict__ ao) {
  int win = blockIdx.x, h = blockIdx.y, b = blockIdx.z;
  int tid = threadIdx.x, lane = tid & 63, wid = tid >> 6;
  int l15 = lane & 15, l4 = lane >> 4;

  __shared__ u16 KPs[64 * 216];  // Ks view [192][40] (15.4KB) / Ps [64][216]
  __shared__ u16 Vts[32 * 200];  // 12.8 KB
  __shared__ unsigned char valid[192];

  int t0 = win * WIN - WIN;

  if (tid < 192) {
    int t = t0 + tid;
    valid[tid] = (t >= 0 && t < S_LEN && amask[b * S_LEN + t] != 0) ? 1 : 0;
  }
  // K: reg-stage into padded [192][40]
#pragma unroll
  for (int cc = 0; cc < 3; ++cc) {
    int chunk = cc * 256 + tid;
    int key = chunk >> 2, c = chunk & 3;
    int t = t0 + key;
    t = t < 0 ? 0 : (t >= S_LEN ? S_LEN - 1 : t);
    f32x4 kd = *(const f32x4*)(qkv + (size_t)(b * S_LEN + t) * 768 + 256 + h * 32 + c * 8);
    *(f32x4*)(KPs + key * 40 + c * 8) = kd;
  }
  // V: transpose-stage into [32][200]
  for (int e = tid; e < 192 * 32; e += 256) {
    int key = e >> 5, d = e & 31;
    int t = t0 + key;
    t = t < 0 ? 0 : (t >= S_LEN ? S_LEN - 1 : t);
    Vts[d * 200 + key] = qkv[(size_t)(b * S_LEN + t) * 768 + 512 + h * 32 + d];
  }
  __syncthreads();

  int qrow = b * S_LEN + win * WIN + wid * 16 + l15;
  f32x4 aq = *(const f32x4*)(qkv + (size_t)qrow * 768 + h * 32 + l4 * 8);

  // QK^T swapped: D[qrow@l15][key@l4*4+j]
  f32x4 sacc[12] = {};
#pragma unroll
  for (int f = 0; f < 12; ++f) {
    f32x4 bk = *(const f32x4*)(KPs + (f * 16 + l15) * 40 + l4 * 8);
    mfma16(sacc[f], bk, aq);
  }
  MFMA_FENCE();

  const float scale = 0.17677669529663687f;  // 1/sqrt(32)
  float mrow = -1e30f;
#pragma unroll
  for (int f = 0; f < 12; ++f) {
    const unsigned char* vp = &valid[f * 16 + l4 * 4];
#pragma unroll
    for (int j = 0; j < 4; ++j) {
      float sv = vp[j] ? sacc[f][j] * scale : -1e9f;
      sacc[f][j] = sv;
      mrow = fmaxf(mrow, sv);
    }
  }
  mrow = fmaxf(mrow, __shfl_xor(mrow, 16, 64));
  mrow = fmaxf(mrow, __shfl_xor(mrow, 32, 64));

  float ssum = 0.f;
#pragma unroll
  for (int f = 0; f < 12; ++f)
#pragma unroll
    for (int j = 0; j < 4; ++j) {
      float p = __expf(sacc[f][j] - mrow);
      sacc[f][j] = p;
      ssum += p;
    }
  ssum += __shfl_xor(ssum, 16, 64);
  ssum += __shfl_xor(ssum, 32, 64);

  __syncthreads();  // all waves done reading Ks before Ps overwrites it

#pragma unroll
  for (int f = 0; f < 12; ++f) {
    u32x2 pk;
    pk[0] = cvt_pk_bf16(sacc[f][0], sacc[f][1]);
    pk[1] = cvt_pk_bf16(sacc[f][2], sacc[f][3]);
    *(u32x2*)(KPs + (wid * 16 + l15) * 216 + f * 16 + l4 * 4) = pk;
  }
  __syncthreads();

  // PV: O[qrow@l15][vcol@l4*4+j]
  f32x4 oacc[2] = {};
#pragma unroll
  for (int kk = 0; kk < 6; ++kk) {
    f32x4 ap = *(const f32x4*)(KPs + (wid * 16 + l15) * 216 + kk * 32 + l4 * 8);
#pragma unroll
    for (int nf = 0; nf < 2; ++nf) {
      f32x4 bvv = *(const f32x4*)(Vts + (nf * 16 + l15) * 200 + kk * 32 + l4 * 8);
      mfma16(oacc[nf], bvv, ap);
    }
  }
  MFMA_FENCE();

  float invv = 1.0f / ssum;
  size_t obase = (size_t)qrow * 256 + h * 32;
#pragma unroll
  for (int nf = 0; nf < 2; ++nf) {
    f32x4 v = oacc[nf] * invv;
    *(u32x2*)(ao + obase + nf * 16 + l4 * 4) = pack_bf16x4(v);
  }
}

// ------------------------------------------------------------- scan --------
__global__ __launch_bounds__(256) void scan_kernel(const int* __restrict__ wsrt,
                                                   int* __restrict__ tgt) {
  __shared__ int part[256];
  int b = blockIdx.x, tid = threadIdx.x;
  const int* src = wsrt + b * S_LEN;
  int* dst = tgt + b * S_LEN;
  int base = tid * 32;
  int loc[32];
  int s = 0;
#pragma unroll
  for (int i = 0; i < 32; ++i) {
    loc[i] = src[base + i];
    s += loc[i];
  }
  part[tid] = s;
  __syncthreads();
  for (int off = 1; off < 256; off <<= 1) {
    int v = (tid >= off) ? part[tid - off] : 0;
    __syncthreads();
    part[tid] += v;
    __syncthreads();
  }
  int cum = part[tid] - s;
#pragma unroll
  for (int i = 0; i < 32; ++i) {
    cum += loc[i];
    dst[base + i] = (loc[i] > 0) ? (cum - 1) : -1;
  }
}

// ------------------------------------------------- final LN + gather -------
__global__ __launch_bounds__(64) void gather_ln_kernel(
    const float* __restrict__ x, const int* __restrict__ tgt,
    const float* __restrict__ g, const float* __restrict__ b,
    float* __restrict__ out) {
  int r = blockIdx.x;
  int tg = tgt[r];
  if (tg < 0) return;
  int bIdx = r >> 13;
  int lane = threadIdx.x;
  f32x4 v = *(const f32x4*)(x + (size_t)r * DMODEL + lane * 4);
  float s = v[0] + v[1] + v[2] + v[3];
  float q = v[0] * v[0] + v[1] * v[1] + v[2] * v[2] + v[3] * v[3];
  for (int off = 32; off; off >>= 1) {
    s += __shfl_xor(s, off, 64);
    q += __shfl_xor(q, off, 64);
  }
  float mean = s * (1.0f / DMODEL);
  float var = q * (1.0f / DMODEL) - mean * mean;
  float rs = rsqrtf(var + 1e-5f);
  f32x4 gg = *(const f32x4*)(g + lane * 4);
  f32x4 bb = *(const f32x4*)(b + lane * 4);
  f32x4 o;
  for (int j = 0; j < 4; ++j) o[j] = (v[j] - mean) * rs * gg[j] + bb[j];
  *(f32x4*)(out + (size_t)(bIdx * S_LEN + tg) * DMODEL + lane * 4) = o;
}

// ---------------------------------------------------------------------------
extern "C" void kernel_launch(void* const* d_in, const int* in_sizes, int n_in,
                              void* d_out, int out_size, void* d_ws,
                              size_t ws_size, hipStream_t stream) {
  const int* ids = (const int*)d_in[0];
  const int* amask = (const int*)d_in[1];
  const int* wstart = (const int*)d_in[2];
  const float* emb = (const float*)d_in[3];
  const float* pos = (const float*)d_in[4];
  const float* ln1g = (const float*)d_in[5];
  const float* ln1b = (const float*)d_in[6];
  const float* wq = (const float*)d_in[7];
  const float* wk = (const float*)d_in[8];
  const float* wv = (const float*)d_in[9];
  const float* wo = (const float*)d_in[10];
  const float* ln2g = (const float*)d_in[11];
  const float* ln2b = (const float*)d_in[12];
  const float* w1 = (const float*)d_in[13];
  const float* b1 = (const float*)d_in[14];
  const float* w2 = (const float*)d_in[15];
  const float* b2 = (const float*)d_in[16];
  const float* lnfg = (const float*)d_in[17];
  const float* lnfb = (const float*)d_in[18];

  char* ws = (char*)d_ws;
  const size_t OFF_X = 0;              // f32 [32768][256]
  const size_t OFF_XB = 33554432;      // bf16 [32768][256]
  const size_t OFF_AO = 50331648;      // bf16 [32768][256]
  const size_t OFF_BIG = 67108864;     // bf16 qkv [32768][768] / ffh [32768][1024]
  const size_t OFF_WQKVT = 134217728;  // bf16 [6][768][256]
  const size_t OFF_WOT = 136577024;    // bf16 [6][256][256]
  const size_t OFF_W1T = 137363456;    // bf16 [6][1024][256]
  const size_t OFF_W2T = 140509184;    // bf16 [6][256][1024]
  const size_t OFF_TGT = 143654912;    // int [32768]
  const size_t NEEDED = 143785984;
  if (ws_size < NEEDED) return;

  float* x = (float*)(ws + OFF_X);
  u16* xb = (u16*)(ws + OFF_XB);
  u16* ao = (u16*)(ws + OFF_AO);
  u16* big = (u16*)(ws + OFF_BIG);
  u16* WqkvT = (u16*)(ws + OFF_WQKVT);
  u16* WoT = (u16*)(ws + OFF_WOT);
  u16* W1T = (u16*)(ws + OFF_W1T);
  u16* W2T = (u16*)(ws + OFF_W2T);
  int* tgt = (int*)(ws + OFF_TGT);

  tcast_kernel<<<1024, 256, 0, stream>>>(wq, WqkvT, NLAYER * 256 * 256, 256, 256, 768 * 256, 0);
  tcast_kernel<<<1024, 256, 0, stream>>>(wk, WqkvT, NLAYER * 256 * 256, 256, 256, 768 * 256, 256);
  tcast_kernel<<<1024, 256, 0, stream>>>(wv, WqkvT, NLAYER * 256 * 256, 256, 256, 768 * 256, 512);
  tcast_kernel<<<1024, 256, 0, stream>>>(wo, WoT, NLAYER * 256 * 256, 256, 256, 256 * 256, 0);
  tcast_kernel<<<2048, 256, 0, stream>>>(w1, W1T, NLAYER * 256 * 1024, 256, 1024, 1024 * 256, 0);
  tcast_kernel<<<2048, 256, 0, stream>>>(w2, W2T, NLAYER * 1024 * 256, 1024, 256, 256 * 1024, 0);

  embed_ln_kernel<<<MROWS / 4, 256, 0, stream>>>(ids, emb, pos, ln1g, ln1b, x, xb);
  zero_kernel<<<2048, 256, 0, stream>>>((float*)d_out, out_size / 4);
  scan_kernel<<<BATCH, 256, 0, stream>>>(wstart, tgt);

  for (int l = 0; l < NLAYER; ++l) {
    gemm_bf16<false, false><<<1536, 256, 0, stream>>>(
        xb, WqkvT + (size_t)l * 768 * 256, big, nullptr, 768, 256, 6);
    attn_kernel<<<dim3(NWIN, NHEAD, BATCH), 256, 0, stream>>>(big, amask, ao);
    gemm_res_ln<true><<<MROWS / 128, 512, 0, stream>>>(
        ao, WoT + (size_t)l * 256 * 256, x, xb, nullptr,
        ln2g + l * DMODEL, ln2b + l * DMODEL, 256);
    gemm_bf16<true, true><<<2048, 256, 0, stream>>>(
        xb, W1T + (size_t)l * 1024 * 256, big, b1 + l * FFDIM, 1024, 256, 8);
    if (l < NLAYER - 1) {
      gemm_res_ln<true><<<MROWS / 128, 512, 0, stream>>>(
          big, W2T + (size_t)l * 256 * 1024, x, xb, b2 + l * DMODEL,
          ln1g + (l + 1) * DMODEL, ln1b + (l + 1) * DMODEL, 1024);
    } else {
      gemm_res_ln<false><<<MROWS / 128, 512, 0, stream>>>(
          big, W2T + (size_t)l * 256 * 1024, x, nullptr, b2 + l * DMODEL,
          nullptr, nullptr, 1024);
    }
  }

  gather_ln_kernel<<<MROWS, 64, 0, stream>>>(x, tgt, lnfg, lnfb, (float*)d_out);
}